// Round 1
// baseline (310.250 us; speedup 1.0000x reference)
//
#include <hip/hip_runtime.h>

// Wave forward: 16 channels, 512x512 grid, 48 leapfrog steps, 4th-order
// circular laplacian. Per-channel 208x208 window around its source (support
// after 48 steps has L-inf radius <= 96; window covers 103/104).

#define GN    512
#define NMASK 511
#define NCH   16
#define NT    48
#define NM    128
#define W     208
#define WOFF  103
#define CELLS_PER_CH   (W * W)            // 43264
#define BLOCKS_PER_CH  (CELLS_PER_CH/256) // 169
#define MAIN_BLOCKS    (NCH * BLOCKS_PER_CH) // 2704
#define GATHER_BLOCKS  8                  // 16*128 = 2048 threads
#define PLANE (GN * GN)                   // 262144

__global__ void coef_kernel(const float* __restrict__ x, float* __restrict__ coef) {
    int idx = blockIdx.x * 256 + threadIdx.x;
    int gi = idx >> 9, gj = idx & NMASK;
    float xp;
    if (gi < 55 || gi >= 457 || gj < 55 || gj >= 457)
        xp = 1e-6f;                       // ABC pad
    else if (gi >= 128 && gi < 384 && gj >= 128 && gj < 384)
        xp = x[(gi - 128) * 256 + (gj - 128)];
    else
        xp = 1.5f;                        // bg pad
    float t = 0.2f * xp;                  // dt*xp/dx
    coef[idx] = t * t;
}

__global__ void step_kernel(const float* __restrict__ pRead,   // f_{j-1}
                            float* __restrict__ pWrite,        // holds f_{j-2}, becomes f_j
                            const float* __restrict__ coef,
                            const int* __restrict__ trans,
                            const int* __restrict__ meas,
                            const float* __restrict__ src,
                            float* __restrict__ out,
                            int j, int mainBlocks)
{
    int b = blockIdx.x;
    if (b < mainBlocks) {
        int r  = b / BLOCKS_PER_CH;
        int lb = b - r * BLOCKS_PER_CH;
        int t  = lb * 256 + (int)threadIdx.x;
        int il = t / W;
        int jl = t - il * W;
        int tr = trans[r];
        int tx = tr >> 9, ty = tr & NMASK;
        int gi = (tx - WOFF + il) & NMASK;
        int gj = (ty - WOFF + jl) & NMASK;
        const float* p1 = pRead + r * PLANE;
        int im1 = (gi - 1) & NMASK, im2 = (gi - 2) & NMASK;
        int ip1 = (gi + 1) & NMASK, ip2 = (gi + 2) & NMASK;
        int jm1 = (gj - 1) & NMASK, jm2 = (gj - 2) & NMASK;
        int jp1 = (gj + 1) & NMASK, jp2 = (gj + 2) & NMASK;
        int rowbase = gi * GN;
        float c0 = p1[rowbase + gj];
        float a1 = p1[im1 * GN + gj], a2 = p1[im2 * GN + gj];
        float a3 = p1[ip1 * GN + gj], a4 = p1[ip2 * GN + gj];
        float b1 = p1[rowbase + jm1], b2 = p1[rowbase + jm2];
        float b3 = p1[rowbase + jp1], b4 = p1[rowbase + jp2];
        float lap = (16.0f * (a1 + a3 + b1 + b3) - (a2 + a4 + b2 + b4) - 60.0f * c0)
                    * (1.0f / 12.0f);
        int idx = r * PLANE + rowbase + gj;
        float pnew = 2.0f * c0 - pWrite[idx] + coef[rowbase + gj] * lap;
        if (gi == tx && gj == ty) pnew += 0.09f * src[j];   // (bg*dt/dx)^2 = 0.09
        pWrite[idx] = pnew;
    } else {
        // gather measurements of step j-1 from pRead (read-only this launch)
        int g = (b - mainBlocks) * 256 + (int)threadIdx.x;
        int jm = j - 1;
        if (g < NCH * NM && jm >= 0) {
            int r = g >> 7, m = g & 127;
            int cell = meas[m];
            out[(r * NM + m) * NT + jm] = pRead[r * PLANE + cell];
        }
    }
}

extern "C" void kernel_launch(void* const* d_in, const int* in_sizes, int n_in,
                              void* d_out, int out_size, void* d_ws, size_t ws_size,
                              hipStream_t stream)
{
    const float* x     = (const float*)d_in[0];
    const float* src   = (const float*)d_in[1];
    const int*   meas  = (const int*)d_in[2];
    const int*   trans = (const int*)d_in[3];
    float* out  = (float*)d_out;

    float* pA   = (float*)d_ws;            // NCH*PLANE floats
    float* pB   = pA + (size_t)NCH * PLANE;
    float* coef = pB + (size_t)NCH * PLANE;
    size_t pbytes = (size_t)NCH * PLANE * sizeof(float);

    hipMemsetAsync(pA, 0, 2 * pbytes, stream);   // zero both field buffers
    coef_kernel<<<PLANE / 256, 256, 0, stream>>>(x, coef);

    float* bufs[2] = { pA, pB };
    for (int j = 0; j < NT; ++j) {
        float* w  = bufs[j & 1];        // holds f_{j-2} -> becomes f_j
        float* rd = bufs[(j & 1) ^ 1];  // f_{j-1}
        step_kernel<<<MAIN_BLOCKS + GATHER_BLOCKS, 256, 0, stream>>>(
            rd, w, coef, trans, meas, src, out, j, MAIN_BLOCKS);
    }
    // trailing gather of step NT-1 from f_{NT-1} = bufs[(NT-1)&1]
    step_kernel<<<GATHER_BLOCKS, 256, 0, stream>>>(
        bufs[(NT - 1) & 1], nullptr, coef, trans, meas, src, out, NT, 0);
}

// Round 2
// 245.164 us; speedup vs baseline: 1.2655x; 1.2655x over previous
//
#include <hip/hip_runtime.h>

// Wave forward, temporally blocked: 16 channels, per-channel 208x208 window,
// 48 leapfrog steps fused 8-at-a-time in LDS (trapezoidal tiles, halo 16).

#define GN     512
#define NMASK  511
#define NCH    16
#define NT     48
#define NM     128
#define WW     208            // window size
#define WOFF   103            // source offset inside window
#define TI     52             // tile interior
#define TS     8              // fused time steps per launch
#define HALO   16             // 2*TS
#define LT     84             // TI + 2*HALO
#define LT2    (LT*LT)
#define WCELLS (WW*WW)        // 43264
#define NLAUNCH (NT/TS)       // 6

__global__ void coef_kernel(const float* __restrict__ x,
                            const int* __restrict__ trans,
                            float* __restrict__ coefw) {
    int idx = blockIdx.x * 256 + threadIdx.x;
    if (idx >= NCH * WCELLS) return;
    int r  = idx / WCELLS;
    int c  = idx - r * WCELLS;
    int li = c / WW, lj = c - (c / WW) * WW;
    int tr = trans[r];
    int ox = (tr >> 9) - WOFF, oy = (tr & NMASK) - WOFF;
    int gi = (ox + li) & NMASK, gj = (oy + lj) & NMASK;
    float xp;
    if (gi < 55 || gi >= 457 || gj < 55 || gj >= 457)
        xp = 1e-6f;                                   // ABC pad
    else if (gi >= 128 && gi < 384 && gj >= 128 && gj < 384)
        xp = x[(gi - 128) * 256 + (gj - 128)];
    else
        xp = 1.5f;                                    // bg pad
    float t = 0.2f * xp;
    coefw[idx] = t * t;
}

__global__ __launch_bounds__(256, 1)
void fused_kernel(const float* __restrict__ g0,   // f_{J-2} windows
                  const float* __restrict__ g1,   // f_{J-1} windows
                  float* __restrict__ h0,         // out f_{J+TS-2}
                  float* __restrict__ h1,         // out f_{J+TS-1}
                  const float* __restrict__ coefw,
                  const int* __restrict__ trans,
                  const int* __restrict__ meas,
                  const float* __restrict__ src,
                  float* __restrict__ out,
                  int J)
{
    __shared__ float buf[2][LT2];
    __shared__ float cof[LT2];
    const int tid = threadIdx.x;
    const int b   = blockIdx.x;
    const int r    = b >> 4;
    const int tile = b & 15;
    const int ri0 = (tile >> 2) * TI - HALO;
    const int rj0 = (tile &  3) * TI - HALO;
    const float* cg0 = g0 + r * WCELLS;
    const float* cg1 = g1 + r * WCELLS;
    const float* cw  = coefw + r * WCELLS;

    // load tile + halo (zero outside window; field there is always zero)
    for (int idx = tid; idx < LT2; idx += 256) {
        int li = idx / LT, lj = idx - (idx / LT) * LT;
        int wr = ri0 + li, wc = rj0 + lj;
        bool in = ((unsigned)wr < WW) && ((unsigned)wc < WW);
        int wi = wr * WW + wc;
        buf[0][idx] = in ? cg0[wi] : 0.0f;
        buf[1][idx] = in ? cg1[wi] : 0.0f;
        cof[idx]    = in ? cw[wi]  : 0.0f;
    }

    // measurement-point ownership (fixed across sub-steps)
    int tr = trans[r];
    int ox = (tr >> 9) - WOFF, oy = (tr & NMASK) - WOFF;
    bool own = false; int mlds = 0; float* mout = nullptr;
    if (tid < NM) {
        int mc = meas[tid];
        int mi = ((mc >> 9)    - ox) & NMASK;   // window-frame coords (torus)
        int mj = ((mc & NMASK) - oy) & NMASK;
        int li = mi - ri0, lj = mj - rj0;
        own  = (li >= HALO && li < HALO + TI && lj >= HALO && lj < HALO + TI);
        mlds = li * LT + lj;
        mout = out + ((size_t)(r * NM + tid)) * NT;
    }
    const int lsi = WOFF - ri0, lsj = WOFF - rj0;  // source local coords
    __syncthreads();

    int A = 0, B = 1;   // A holds f_{s-2} (overwritten in place), B holds f_{s-1}
    for (int s = 0; s < TS; ++s) {
        float sv = 0.09f * src[J + s];             // (bg*dt/dx)^2 = 0.09
        int lo = 2 * (s + 1), hi = LT - lo;
        int tx = tid & 31, ty = tid >> 5;
        for (int li = lo + ty; li < hi; li += 8) {
            int rb = li * LT;
            for (int lj = lo + tx; lj < hi; lj += 32) {
                float c0  = buf[B][rb + lj];
                float vm1 = buf[B][rb - LT + lj],   vm2 = buf[B][rb - 2*LT + lj];
                float vp1 = buf[B][rb + LT + lj],   vp2 = buf[B][rb + 2*LT + lj];
                float hm1 = buf[B][rb + lj - 1],    hm2 = buf[B][rb + lj - 2];
                float hp1 = buf[B][rb + lj + 1],    hp2 = buf[B][rb + lj + 2];
                float lap = (16.0f * (vm1 + vp1 + hm1 + hp1)
                             - (vm2 + vp2 + hm2 + hp2) - 60.0f * c0) * (1.0f/12.0f);
                float pnew = 2.0f * c0 - buf[A][rb + lj] + cof[rb + lj] * lap;
                if (li == lsi && lj == lsj) pnew += sv;
                buf[A][rb + lj] = pnew;
            }
        }
        __syncthreads();
        A ^= 1; B ^= 1;                            // B now newest = f_{J+s}
        if (own) mout[J + s] = buf[B][mlds];       // record measurement
    }

    // write back interior of both final levels (tiles partition the window)
    float* ch0 = h0 + r * WCELLS;
    float* ch1 = h1 + r * WCELLS;
    for (int idx = tid; idx < TI * TI; idx += 256) {
        int li = idx / TI, lj = idx - (idx / TI) * TI;
        int l = (li + HALO) * LT + (lj + HALO);
        int w = (ri0 + HALO + li) * WW + (rj0 + HALO + lj);
        ch1[w] = buf[B][l];
        ch0[w] = buf[A][l];
    }
}

extern "C" void kernel_launch(void* const* d_in, const int* in_sizes, int n_in,
                              void* d_out, int out_size, void* d_ws, size_t ws_size,
                              hipStream_t stream)
{
    const float* x     = (const float*)d_in[0];
    const float* src   = (const float*)d_in[1];
    const int*   meas  = (const int*)d_in[2];
    const int*   trans = (const int*)d_in[3];
    float* out = (float*)d_out;

    float* P0    = (float*)d_ws;                 // src pair (levels J-2, J-1)
    float* P1    = P0 + (size_t)NCH * WCELLS;
    float* Q0    = P1 + (size_t)NCH * WCELLS;    // dst pair
    float* Q1    = Q0 + (size_t)NCH * WCELLS;
    float* coefw = Q1 + (size_t)NCH * WCELLS;

    // zero initial fields (P0,P1 contiguous) and the output
    hipMemsetAsync(P0, 0, 2 * (size_t)NCH * WCELLS * sizeof(float), stream);
    hipMemsetAsync(out, 0, (size_t)out_size * sizeof(float), stream);

    coef_kernel<<<(NCH * WCELLS + 255) / 256, 256, 0, stream>>>(x, trans, coefw);

    float *s0 = P0, *s1 = P1, *t0 = Q0, *t1 = Q1;
    for (int k = 0; k < NLAUNCH; ++k) {
        fused_kernel<<<256, 256, 0, stream>>>(s0, s1, t0, t1, coefw,
                                              trans, meas, src, out, k * TS);
        float* tmp;
        tmp = s0; s0 = t0; t0 = tmp;
        tmp = s1; s1 = t1; t1 = tmp;
    }
}

// Round 3
// 91.824 us; speedup vs baseline: 3.3788x; 2.6699x over previous
//
#include <hip/hip_runtime.h>

// Wave forward: 16 channels, 208x208 window/channel, 48 steps fused 8/launch.
// Register-blocked: each thread owns a 4x4 cell block; coef + two time levels
// in registers; LDS holds only the current field (ping-pong), accessed purely
// via ds_read_b128/ds_write_b128 (1 LDS instr per cell update).

#define GN     512
#define NMASK  511
#define NCH    16
#define NT     48
#define NM     128
#define WW     208            // window size
#define WOFF   103            // source offset inside window
#define TI     52             // tile interior
#define TS     8              // fused time steps per launch
#define HALO   16             // 2*TS
#define LT     84             // TI + 2*HALO
#define LT2    (LT*LT)
#define WCELLS (WW*WW)        // 43264
#define NLAUNCH (NT/TS)       // 6
#define NTH    448            // 7 waves
#define NACT   441            // 21x21 threads of 4x4 cells = 84^2

__global__ void coef_kernel(const float* __restrict__ x,
                            const int* __restrict__ trans,
                            float* __restrict__ coefw) {
    int idx = blockIdx.x * 256 + threadIdx.x;
    if (idx >= NCH * WCELLS) return;
    int r  = idx / WCELLS;
    int c  = idx - r * WCELLS;
    int li = c / WW, lj = c - (c / WW) * WW;
    int tr = trans[r];
    int ox = (tr >> 9) - WOFF, oy = (tr & NMASK) - WOFF;
    int gi = (ox + li) & NMASK, gj = (oy + lj) & NMASK;
    float xp;
    if (gi < 55 || gi >= 457 || gj < 55 || gj >= 457)
        xp = 1e-6f;                                   // ABC pad
    else if (gi >= 128 && gi < 384 && gj >= 128 && gj < 384)
        xp = x[(gi - 128) * 256 + (gj - 128)];
    else
        xp = 1.5f;                                    // bg pad
    float t = 0.2f * xp;
    coefw[idx] = t * t;
}

__device__ __forceinline__ float4 ld4(const float* p) { return *(const float4*)p; }
__device__ __forceinline__ void st4(float* p, float4 v) { *(float4*)p = v; }

__global__ __launch_bounds__(NTH, 1)
void fused_kernel(const float* __restrict__ g0,   // f_{J-2} windows
                  const float* __restrict__ g1,   // f_{J-1} windows
                  float* __restrict__ h0,         // out f_{J+TS-2}
                  float* __restrict__ h1,         // out f_{J+TS-1}
                  const float* __restrict__ coefw,
                  const int* __restrict__ trans,
                  const int* __restrict__ meas,
                  const float* __restrict__ src,
                  float* __restrict__ out,
                  int J)
{
    __shared__ float lds0[LT2];
    __shared__ float lds1[LT2];
    const int tid  = threadIdx.x;
    const int b    = blockIdx.x;
    const int r    = b >> 4;
    const int tile = b & 15;
    const int ri0  = (tile >> 2) * TI - HALO;
    const int rj0  = (tile &  3) * TI - HALO;
    const float* cg0 = g0 + r * WCELLS;
    const float* cg1 = g1 + r * WCELLS;
    const float* cw  = coefw + r * WCELLS;

    // stage f_{J-1} tile into lds0 (zero outside window; field is 0 there)
    for (int q = tid; q < LT2 / 4; q += NTH) {
        int li = q / (LT / 4);
        int lj = (q - li * (LT / 4)) * 4;
        int wr = ri0 + li, wc = rj0 + lj;
        float4 v = make_float4(0.f, 0.f, 0.f, 0.f);
        if ((unsigned)wr < WW && (unsigned)wc < WW)
            v = ld4(cg1 + wr * WW + wc);
        st4(&lds0[li * LT + lj], v);
    }

    const bool active = tid < NACT;
    const int ty = tid / 21, tx = tid - 21 * (tid / 21);
    const int li0 = 4 * ty, lj0 = 4 * tx;

    // per-thread register state: C = f_{s-1} own cells, P = f_{s-2}, K = coef
    float C[16], P[16], K[16];
    int offT2 = 0, offT1 = 0, offB1 = 0, offB2 = 0;
    int offL[4] = {0,0,0,0}, offR[4] = {0,0,0,0}, offC[4] = {0,0,0,0};
    unsigned smask = 0;
    if (active) {
        #pragma unroll
        for (int rr = 0; rr < 4; ++rr) {
            int wr = ri0 + li0 + rr, wc = rj0 + lj0;
            float4 vc = make_float4(0,0,0,0), vp = vc, vk = vc;
            if ((unsigned)wr < WW && (unsigned)wc < WW) {
                vc = ld4(cg1 + wr * WW + wc);
                vp = ld4(cg0 + wr * WW + wc);
                vk = ld4(cw  + wr * WW + wc);
            }
            C[rr*4+0]=vc.x; C[rr*4+1]=vc.y; C[rr*4+2]=vc.z; C[rr*4+3]=vc.w;
            P[rr*4+0]=vp.x; P[rr*4+1]=vp.y; P[rr*4+2]=vp.z; P[rr*4+3]=vp.w;
            K[rr*4+0]=vk.x; K[rr*4+1]=vk.y; K[rr*4+2]=vk.z; K[rr*4+3]=vk.w;
        }
        int rT2 = li0 - 2 < 0 ? 0 : li0 - 2;
        int rT1 = li0 - 1 < 0 ? 0 : li0 - 1;
        int rB1 = li0 + 4 > LT - 1 ? LT - 1 : li0 + 4;
        int rB2 = li0 + 5 > LT - 1 ? LT - 1 : li0 + 5;
        offT2 = rT2 * LT + lj0;  offT1 = rT1 * LT + lj0;
        offB1 = rB1 * LT + lj0;  offB2 = rB2 * LT + lj0;
        #pragma unroll
        for (int rr = 0; rr < 4; ++rr) {
            int base = (li0 + rr) * LT + lj0;
            offC[rr] = base;
            int ol = base - 4;  if (ol < 0) ol = 0;
            int orr = base + 4; if (orr > LT2 - 4) orr = LT2 - 4;
            offL[rr] = ol; offR[rr] = orr;
        }
        // source injection mask ((bg*dt/dx)^2 = 0.09 applied via sv)
        int si = (WOFF - ri0) - li0, sj = (WOFF - rj0) - lj0;
        if (si >= 0 && si < 4 && sj >= 0 && sj < 4) smask = 1u << (si * 4 + sj);
    }

    // measurement ownership (interior cells only; fixed across substeps)
    bool mvalid = false; int mlds = 0; float* mout = nullptr;
    {
        int tr = trans[r];
        int ox = (tr >> 9) - WOFF, oy = (tr & NMASK) - WOFF;
        if (tid < NM) {
            int mc = meas[tid];
            int mi = ((mc >> 9)    - ox) & NMASK;
            int mj = ((mc & NMASK) - oy) & NMASK;
            int li = mi - ri0, lj = mj - rj0;
            mvalid = (li >= HALO && li < HALO + TI && lj >= HALO && lj < HALO + TI);
            mlds = li * LT + lj;
            mout = out + (size_t)(r * NM + tid) * NT;
        }
    }

    float sv[TS];
    #pragma unroll
    for (int s = 0; s < TS; ++s) sv[s] = 0.09f * src[J + s];

    __syncthreads();

    // one leapfrog substep: A (f_{s-2}) <- f_s, reading B (f_{s-1}) + LDS halo
    auto step1 = [&](float (&A)[16], float (&B)[16],
                     const float* rd, float* wb, float sval, int jj) {
        if (active) {
            float t2[4], t1[4], b1a[4], b2a[4];
            float4 v;
            v = ld4(rd + offT2); t2[0]=v.x;  t2[1]=v.y;  t2[2]=v.z;  t2[3]=v.w;
            v = ld4(rd + offT1); t1[0]=v.x;  t1[1]=v.y;  t1[2]=v.z;  t1[3]=v.w;
            v = ld4(rd + offB1); b1a[0]=v.x; b1a[1]=v.y; b1a[2]=v.z; b1a[3]=v.w;
            v = ld4(rd + offB2); b2a[0]=v.x; b2a[1]=v.y; b2a[2]=v.z; b2a[3]=v.w;
            float Lw[4][4], Rw[4][4];
            #pragma unroll
            for (int rr = 0; rr < 4; ++rr) {
                v = ld4(rd + offL[rr]); Lw[rr][0]=v.x; Lw[rr][1]=v.y; Lw[rr][2]=v.z; Lw[rr][3]=v.w;
                v = ld4(rd + offR[rr]); Rw[rr][0]=v.x; Rw[rr][1]=v.y; Rw[rr][2]=v.z; Rw[rr][3]=v.w;
            }
            #pragma unroll
            for (int rr = 0; rr < 4; ++rr) {
                float w[12];
                w[0]=Lw[rr][0]; w[1]=Lw[rr][1]; w[2]=Lw[rr][2];  w[3]=Lw[rr][3];
                w[4]=B[rr*4+0]; w[5]=B[rr*4+1]; w[6]=B[rr*4+2];  w[7]=B[rr*4+3];
                w[8]=Rw[rr][0]; w[9]=Rw[rr][1]; w[10]=Rw[rr][2]; w[11]=Rw[rr][3];
                #pragma unroll
                for (int cc = 0; cc < 4; ++cc) {
                    float vm2 = (rr == 0) ? t2[cc]  : (rr == 1) ? t1[cc]  : B[(rr-2)*4+cc];
                    float vm1 = (rr == 0) ? t1[cc]  : B[(rr-1)*4+cc];
                    float vp1 = (rr == 3) ? b1a[cc] : B[(rr+1)*4+cc];
                    float vp2 = (rr == 3) ? b2a[cc] : (rr == 2) ? b1a[cc] : B[(rr+2)*4+cc];
                    float c0  = w[4+cc];
                    float lap = (16.f * (w[3+cc] + w[5+cc] + vm1 + vp1)
                                 - (w[2+cc] + w[6+cc] + vm2 + vp2)
                                 - 60.f * c0) * (1.f / 12.f);
                    float pn = 2.f * c0 - A[rr*4+cc] + K[rr*4+cc] * lap;
                    if (smask & (1u << (rr*4+cc))) pn += sval;
                    A[rr*4+cc] = pn;
                }
                st4(wb + offC[rr],
                    make_float4(A[rr*4+0], A[rr*4+1], A[rr*4+2], A[rr*4+3]));
            }
        }
        __syncthreads();
        if (mvalid) mout[jj] = wb[mlds];
    };

    step1(P, C, lds0, lds1, sv[0], J + 0);
    step1(C, P, lds1, lds0, sv[1], J + 1);
    step1(P, C, lds0, lds1, sv[2], J + 2);
    step1(C, P, lds1, lds0, sv[3], J + 3);
    step1(P, C, lds0, lds1, sv[4], J + 4);
    step1(C, P, lds1, lds0, sv[5], J + 5);
    step1(P, C, lds0, lds1, sv[6], J + 6);
    step1(C, P, lds1, lds0, sv[7], J + 7);
    // now C = f_{J+7}, P = f_{J+6}

    // write back interior (threads tx,ty in [4,16] own exactly the 52^2 interior)
    if (active && tx >= 4 && tx <= 16 && ty >= 4 && ty <= 16) {
        float* ch0 = h0 + r * WCELLS;
        float* ch1 = h1 + r * WCELLS;
        #pragma unroll
        for (int rr = 0; rr < 4; ++rr) {
            int wi = (ri0 + li0 + rr) * WW + (rj0 + lj0);
            st4(ch1 + wi, make_float4(C[rr*4+0], C[rr*4+1], C[rr*4+2], C[rr*4+3]));
            st4(ch0 + wi, make_float4(P[rr*4+0], P[rr*4+1], P[rr*4+2], P[rr*4+3]));
        }
    }
}

extern "C" void kernel_launch(void* const* d_in, const int* in_sizes, int n_in,
                              void* d_out, int out_size, void* d_ws, size_t ws_size,
                              hipStream_t stream)
{
    const float* x     = (const float*)d_in[0];
    const float* src   = (const float*)d_in[1];
    const int*   meas  = (const int*)d_in[2];
    const int*   trans = (const int*)d_in[3];
    float* out = (float*)d_out;

    float* P0    = (float*)d_ws;                 // src pair (levels J-2, J-1)
    float* P1    = P0 + (size_t)NCH * WCELLS;
    float* Q0    = P1 + (size_t)NCH * WCELLS;    // dst pair
    float* Q1    = Q0 + (size_t)NCH * WCELLS;
    float* coefw = Q1 + (size_t)NCH * WCELLS;

    hipMemsetAsync(P0, 0, 2 * (size_t)NCH * WCELLS * sizeof(float), stream);
    hipMemsetAsync(out, 0, (size_t)out_size * sizeof(float), stream);

    coef_kernel<<<(NCH * WCELLS + 255) / 256, 256, 0, stream>>>(x, trans, coefw);

    float *s0 = P0, *s1 = P1, *t0 = Q0, *t1 = Q1;
    for (int k = 0; k < NLAUNCH; ++k) {
        fused_kernel<<<256, NTH, 0, stream>>>(s0, s1, t0, t1, coefw,
                                              trans, meas, src, out, k * TS);
        float* tmp;
        tmp = s0; s0 = t0; t0 = tmp;
        tmp = s1; s1 = t1; t1 = tmp;
    }
}